// Round 1
// baseline (383.838 us; speedup 1.0000x reference)
//
#include <hip/hip_runtime.h>

#define N_FEAT 50
#define HID 16
#define NC 10

// ---------------- kernels ----------------

__global__ void deg_kernel(const int* __restrict__ dst, int E, int* __restrict__ degi) {
    int e = blockIdx.x * blockDim.x + threadIdx.x;
    if (e < E) atomicAdd(&degi[dst[e]], 1);
}

__global__ void dinv_kernel(const int* __restrict__ degi, int n, float* __restrict__ dinv) {
    int i = blockIdx.x * blockDim.x + threadIdx.x;
    if (i < n) {
        int d = degi[i];
        dinv[i] = (d > 0) ? rsqrtf((float)d) : 0.0f;
    }
}

// Per node: s1 = x @ w1_0 ; t1s = dinv[node] * (x @ w1_1)
__global__ void node1_kernel(const float* __restrict__ x,
                             const float* __restrict__ w10,
                             const float* __restrict__ w11,
                             const float* __restrict__ dinv,
                             int n,
                             float* __restrict__ s1,
                             float* __restrict__ t1s) {
    __shared__ float sw0[N_FEAT * HID];
    __shared__ float sw1[N_FEAT * HID];
    for (int i = threadIdx.x; i < N_FEAT * HID; i += blockDim.x) {
        sw0[i] = w10[i];
        sw1[i] = w11[i];
    }
    __syncthreads();
    int node = blockIdx.x * blockDim.x + threadIdx.x;
    if (node >= n) return;

    float xr[N_FEAT];
    const float* xp = x + (size_t)node * N_FEAT;
#pragma unroll
    for (int i = 0; i < N_FEAT; i++) xr[i] = xp[i];

    float di = dinv[node];
    float* s1p = s1 + (size_t)node * HID;
    float* tp  = t1s + (size_t)node * HID;
#pragma unroll
    for (int j = 0; j < HID; j++) {
        float a0 = 0.f, a1 = 0.f;
#pragma unroll
        for (int i = 0; i < N_FEAT; i++) {
            a0 += xr[i] * sw0[i * HID + j];
            a1 += xr[i] * sw1[i * HID + j];
        }
        s1p[j] = a0;
        tp[j]  = di * a1;
    }
}

// 16 threads per edge: acc16[dst*16+j] += t1s[src*16+j]
__global__ void scatter16_kernel(const int* __restrict__ src, const int* __restrict__ dst,
                                 int E,
                                 const float* __restrict__ t1s,
                                 float* __restrict__ acc16) {
    int t = blockIdx.x * blockDim.x + threadIdx.x;
    int e = t >> 4;
    int j = t & 15;
    if (e >= E) return;
    int s = src[e];
    int d = dst[e];
    atomicAdd(&acc16[(size_t)d * HID + j], t1s[(size_t)s * HID + j]);
}

// Per node: h = relu(s1 + dinv*acc16 + b1); s2 = h @ w2_0; ps = dinv * (h @ w2_1)
__global__ void node2_kernel(const float* __restrict__ s1,
                             const float* __restrict__ acc16,
                             const float* __restrict__ dinv,
                             const float* __restrict__ b1,
                             const float* __restrict__ w20,
                             const float* __restrict__ w21,
                             int n,
                             float* __restrict__ s2,
                             float* __restrict__ ps) {
    __shared__ float sw0[HID * NC];
    __shared__ float sw1[HID * NC];
    __shared__ float sb1[HID];
    for (int i = threadIdx.x; i < HID * NC; i += blockDim.x) {
        sw0[i] = w20[i];
        sw1[i] = w21[i];
    }
    if (threadIdx.x < HID) sb1[threadIdx.x] = b1[threadIdx.x];
    __syncthreads();
    int node = blockIdx.x * blockDim.x + threadIdx.x;
    if (node >= n) return;

    float di = dinv[node];
    float h[HID];
    const float* s1p = s1 + (size_t)node * HID;
    const float* ap  = acc16 + (size_t)node * HID;
#pragma unroll
    for (int j = 0; j < HID; j++) {
        float v = s1p[j] + di * ap[j] + sb1[j];
        h[j] = v > 0.f ? v : 0.f;
    }
    float* s2p = s2 + (size_t)node * NC;
    float* pp  = ps + (size_t)node * NC;
#pragma unroll
    for (int c = 0; c < NC; c++) {
        float a0 = 0.f, a1 = 0.f;
#pragma unroll
        for (int j = 0; j < HID; j++) {
            a0 += h[j] * sw0[j * NC + c];
            a1 += h[j] * sw1[j * NC + c];
        }
        s2p[c] = a0;
        pp[c]  = di * a1;
    }
}

// 10 threads per edge (t/10): acc10[dst*10+j] += ps[src*10+j]
__global__ void scatter10_kernel(const int* __restrict__ src, const int* __restrict__ dst,
                                 int E,
                                 const float* __restrict__ ps,
                                 float* __restrict__ acc10) {
    int t = blockIdx.x * blockDim.x + threadIdx.x;
    int e = t / NC;
    int j = t - e * NC;
    if (e >= E) return;
    int s = src[e];
    int d = dst[e];
    atomicAdd(&acc10[(size_t)d * NC + j], ps[(size_t)s * NC + j]);
}

// out = log_softmax(s2 + dinv*acc10 + b2)
__global__ void final_kernel(const float* __restrict__ s2,
                             const float* __restrict__ acc10,
                             const float* __restrict__ dinv,
                             const float* __restrict__ b2,
                             int n,
                             float* __restrict__ out) {
    int node = blockIdx.x * blockDim.x + threadIdx.x;
    if (node >= n) return;
    float di = dinv[node];
    const float* s2p = s2 + (size_t)node * NC;
    const float* ap  = acc10 + (size_t)node * NC;
    float v[NC];
    float mx = -1e30f;
#pragma unroll
    for (int c = 0; c < NC; c++) {
        v[c] = s2p[c] + di * ap[c] + b2[c];
        mx = fmaxf(mx, v[c]);
    }
    float se = 0.f;
#pragma unroll
    for (int c = 0; c < NC; c++) se += expf(v[c] - mx);
    float ls = logf(se);
    float* op = out + (size_t)node * NC;
#pragma unroll
    for (int c = 0; c < NC; c++) op[c] = v[c] - mx - ls;
}

// ---------------- launch ----------------

extern "C" void kernel_launch(void* const* d_in, const int* in_sizes, int n_in,
                              void* d_out, int out_size, void* d_ws, size_t ws_size,
                              hipStream_t stream) {
    const float* x    = (const float*)d_in[0];
    const int*   ei   = (const int*)d_in[1];
    const float* w10  = (const float*)d_in[2];
    const float* w11  = (const float*)d_in[3];
    const float* b1   = (const float*)d_in[4];
    const float* w20  = (const float*)d_in[5];
    const float* w21  = (const float*)d_in[6];
    const float* b2   = (const float*)d_in[7];
    float* out = (float*)d_out;

    int n = in_sizes[0] / N_FEAT;   // 100000
    int E = in_sizes[1] / 2;        // 1600000
    const int* src = ei;
    const int* dst = ei + E;

    auto align256 = [](size_t v) { return (v + 255) & ~(size_t)255; };

    size_t off = 0;
    int*   degi  = (int*)((char*)d_ws + off);   off = align256(off + (size_t)n * 4);
    float* acc16 = (float*)((char*)d_ws + off); off = align256(off + (size_t)n * HID * 4);
    float* acc10 = (float*)((char*)d_ws + off); off = align256(off + (size_t)n * NC * 4);
    size_t zero_bytes = off;  // degi + acc16 + acc10 must be zeroed
    float* dinv = (float*)((char*)d_ws + off);  off = align256(off + (size_t)n * 4);
    float* s1   = (float*)((char*)d_ws + off);  off = align256(off + (size_t)n * HID * 4);
    float* t1s  = (float*)((char*)d_ws + off);  off = align256(off + (size_t)n * HID * 4);
    float* s2   = (float*)((char*)d_ws + off);  off = align256(off + (size_t)n * NC * 4);
    float* ps   = (float*)((char*)d_ws + off);  off = align256(off + (size_t)n * NC * 4);

    hipMemsetAsync(d_ws, 0, zero_bytes, stream);

    const int B = 256;
    deg_kernel<<<(E + B - 1) / B, B, 0, stream>>>(dst, E, degi);
    dinv_kernel<<<(n + B - 1) / B, B, 0, stream>>>(degi, n, dinv);
    node1_kernel<<<(n + B - 1) / B, B, 0, stream>>>(x, w10, w11, dinv, n, s1, t1s);
    {
        long long tot = (long long)E * HID;
        scatter16_kernel<<<(int)((tot + B - 1) / B), B, 0, stream>>>(src, dst, E, t1s, acc16);
    }
    node2_kernel<<<(n + B - 1) / B, B, 0, stream>>>(s1, acc16, dinv, b1, w20, w21, n, s2, ps);
    {
        long long tot = (long long)E * NC;
        scatter10_kernel<<<(int)((tot + B - 1) / B), B, 0, stream>>>(src, dst, E, ps, acc10);
    }
    final_kernel<<<(n + B - 1) / B, B, 0, stream>>>(s2, acc10, dinv, b2, n, out);
}

// Round 2
// 341.761 us; speedup vs baseline: 1.1231x; 1.1231x over previous
//
#include <hip/hip_runtime.h>

#define N_FEAT 50
#define HID 16
#define NC 10
#define TPB 256
#define SCAN_VPT 4
#define SCAN_CHUNK (TPB * SCAN_VPT)   // 1024

// ---------------- degree / dinv ----------------

__global__ void deg_kernel(const int* __restrict__ dst, int E, int* __restrict__ degi) {
    int e = blockIdx.x * blockDim.x + threadIdx.x;
    if (e < E) atomicAdd(&degi[dst[e]], 1);
}

__global__ void dinv_kernel(const int* __restrict__ degi, int n, float* __restrict__ dinv) {
    int i = blockIdx.x * blockDim.x + threadIdx.x;
    if (i < n) {
        int d = degi[i];
        dinv[i] = (d > 0) ? rsqrtf((float)d) : 0.0f;
    }
}

// ---------------- exclusive scan (rowptr) ----------------

__global__ void scan_blocks(const int* __restrict__ deg, int n,
                            int* __restrict__ lscan, int* __restrict__ bsums) {
    __shared__ int lds[TPB];
    int base = blockIdx.x * SCAN_CHUNK;
    int t = threadIdx.x;
    int v[SCAN_VPT];
    int sum = 0;
    int idx0 = base + t * SCAN_VPT;
#pragma unroll
    for (int i = 0; i < SCAN_VPT; i++) {
        int idx = idx0 + i;
        v[i] = (idx < n) ? deg[idx] : 0;
        sum += v[i];
    }
    lds[t] = sum;
    __syncthreads();
    for (int off = 1; off < TPB; off <<= 1) {
        int val = lds[t];
        int add = (t >= off) ? lds[t - off] : 0;
        __syncthreads();
        lds[t] = val + add;
        __syncthreads();
    }
    if (t == TPB - 1) bsums[blockIdx.x] = lds[TPB - 1];
    int run = (t == 0) ? 0 : lds[t - 1];
#pragma unroll
    for (int i = 0; i < SCAN_VPT; i++) {
        int idx = idx0 + i;
        if (idx < n) lscan[idx] = run;
        run += v[i];
    }
}

__global__ void scan_bsums(int* __restrict__ bsums, int nb) {
    if (threadIdx.x == 0 && blockIdx.x == 0) {
        int run = 0;
        for (int i = 0; i < nb; i++) { int v = bsums[i]; bsums[i] = run; run += v; }
    }
}

__global__ void scan_add(int* __restrict__ rowptr, int n, const int* __restrict__ bsums, int E) {
    int i = blockIdx.x * blockDim.x + threadIdx.x;
    if (i < n) rowptr[i] += bsums[i / SCAN_CHUNK];
    if (i == 0) rowptr[n] = E;
}

// ---------------- CSR fill ----------------

__global__ void fill_kernel(const int* __restrict__ src, const int* __restrict__ dst, int E,
                            const int* __restrict__ rowptr, int* __restrict__ cnt,
                            int* __restrict__ esrc) {
    int e = blockIdx.x * blockDim.x + threadIdx.x;
    if (e >= E) return;
    int d = dst[e];
    int pos = rowptr[d] + atomicAdd(&cnt[d], 1);
    esrc[pos] = src[e];
}

// ---------------- layer-1 node matmuls ----------------
// s1 = x @ w1_0 ; t1s = dinv[node] * (x @ w1_1)   (t1s stride 16)

__global__ void node1_kernel(const float* __restrict__ x,
                             const float* __restrict__ w10,
                             const float* __restrict__ w11,
                             const float* __restrict__ dinv,
                             int n,
                             float* __restrict__ s1,
                             float* __restrict__ t1s) {
    __shared__ float sw0[N_FEAT * HID];
    __shared__ float sw1[N_FEAT * HID];
    __shared__ float sx[TPB * (N_FEAT + 1)];   // pad 51 to break bank conflicts
    for (int i = threadIdx.x; i < N_FEAT * HID; i += TPB) {
        sw0[i] = w10[i];
        sw1[i] = w11[i];
    }
    int base = blockIdx.x * TPB;
    int cnt = n - base; if (cnt > TPB) cnt = TPB;
    for (int idx = threadIdx.x; idx < cnt * N_FEAT; idx += TPB) {
        int ln = idx / N_FEAT;
        int c  = idx - ln * N_FEAT;
        sx[ln * (N_FEAT + 1) + c] = x[(size_t)base * N_FEAT + idx];
    }
    __syncthreads();
    int local = threadIdx.x;
    int node = base + local;
    if (node >= n) return;

    float xr[N_FEAT];
#pragma unroll
    for (int i = 0; i < N_FEAT; i++) xr[i] = sx[local * (N_FEAT + 1) + i];

    float di = dinv[node];
    float* s1p = s1 + (size_t)node * HID;
    float* tp  = t1s + (size_t)node * HID;
#pragma unroll
    for (int j = 0; j < HID; j++) {
        float a0 = 0.f, a1 = 0.f;
#pragma unroll
        for (int i = 0; i < N_FEAT; i++) {
            a0 += xr[i] * sw0[i * HID + j];
            a1 += xr[i] * sw1[i * HID + j];
        }
        s1p[j] = a0;
        tp[j]  = di * a1;
    }
}

// ---------------- layer-1 gather + relu (in-place h over s1) ----------------
// thread (node,q) q<4: accumulates float4 over edges; h = relu(s1 + di*agg + b1)

__global__ void gather_h(const int* __restrict__ rowptr, const int* __restrict__ esrc,
                         const float4* __restrict__ t1s4,   // [n*4] float4
                         const float* __restrict__ dinv,
                         const float* __restrict__ b1,
                         float4* __restrict__ h4,           // in-place: aliases s1
                         int n) {
    int t = blockIdx.x * blockDim.x + threadIdx.x;
    int node = t >> 2;
    int q = t & 3;
    if (node >= n) return;
    int beg = rowptr[node], end = rowptr[node + 1];
    float4 acc = make_float4(0.f, 0.f, 0.f, 0.f);
    int k = beg;
    for (; k + 1 < end; k += 2) {
        int s0 = esrc[k];
        int s1i = esrc[k + 1];
        float4 a = t1s4[(size_t)s0 * 4 + q];
        float4 b = t1s4[(size_t)s1i * 4 + q];
        acc.x += a.x + b.x; acc.y += a.y + b.y;
        acc.z += a.z + b.z; acc.w += a.w + b.w;
    }
    if (k < end) {
        int s0 = esrc[k];
        float4 a = t1s4[(size_t)s0 * 4 + q];
        acc.x += a.x; acc.y += a.y; acc.z += a.z; acc.w += a.w;
    }
    float di = dinv[node];
    float4 s = h4[(size_t)node * 4 + q];            // s1 (in-place)
    float4 bb = ((const float4*)b1)[q];
    float4 r;
    r.x = fmaxf(s.x + di * acc.x + bb.x, 0.f);
    r.y = fmaxf(s.y + di * acc.y + bb.y, 0.f);
    r.z = fmaxf(s.z + di * acc.z + bb.z, 0.f);
    r.w = fmaxf(s.w + di * acc.w + bb.w, 0.f);
    h4[(size_t)node * 4 + q] = r;
}

// ---------------- layer-2 node matmuls ----------------
// s2 = h @ w2_0 (stride 10); ps16 = dinv * (h @ w2_1), padded to stride 16, zeros in 10..15

__global__ void node2_kernel(const float* __restrict__ h,
                             const float* __restrict__ dinv,
                             const float* __restrict__ w20,
                             const float* __restrict__ w21,
                             int n,
                             float* __restrict__ s2,
                             float* __restrict__ ps16) {
    __shared__ float sw0[HID * NC];
    __shared__ float sw1[HID * NC];
    for (int i = threadIdx.x; i < HID * NC; i += TPB) {
        sw0[i] = w20[i];
        sw1[i] = w21[i];
    }
    __syncthreads();
    int node = blockIdx.x * blockDim.x + threadIdx.x;
    if (node >= n) return;

    float hr[HID];
    const float* hp = h + (size_t)node * HID;
#pragma unroll
    for (int j = 0; j < HID; j++) hr[j] = hp[j];

    float di = dinv[node];
    float* s2p = s2 + (size_t)node * NC;
    float* pp  = ps16 + (size_t)node * 16;
#pragma unroll
    for (int c = 0; c < NC; c++) {
        float a0 = 0.f, a1 = 0.f;
#pragma unroll
        for (int j = 0; j < HID; j++) {
            a0 += hr[j] * sw0[j * NC + c];
            a1 += hr[j] * sw1[j * NC + c];
        }
        s2p[c] = a0;
        pp[c]  = di * a1;
    }
#pragma unroll
    for (int c = NC; c < 16; c++) pp[c] = 0.f;
}

// ---------------- layer-2 gather (in-place v over s2) ----------------

__global__ void gather_v(const int* __restrict__ rowptr, const int* __restrict__ esrc,
                         const float4* __restrict__ ps4,    // [n*4] float4 (stride-16 floats)
                         const float* __restrict__ dinv,
                         const float* __restrict__ b2,
                         float* __restrict__ v,             // in-place: aliases s2 (stride 10)
                         int n) {
    int t = blockIdx.x * blockDim.x + threadIdx.x;
    int node = t >> 2;
    int q = t & 3;
    if (node >= n) return;
    int beg = rowptr[node], end = rowptr[node + 1];
    float4 acc = make_float4(0.f, 0.f, 0.f, 0.f);
    int k = beg;
    for (; k + 1 < end; k += 2) {
        int s0 = esrc[k];
        int s1i = esrc[k + 1];
        float4 a = ps4[(size_t)s0 * 4 + q];
        float4 b = ps4[(size_t)s1i * 4 + q];
        acc.x += a.x + b.x; acc.y += a.y + b.y;
        acc.z += a.z + b.z; acc.w += a.w + b.w;
    }
    if (k < end) {
        int s0 = esrc[k];
        float4 a = ps4[(size_t)s0 * 4 + q];
        acc.x += a.x; acc.y += a.y; acc.z += a.z; acc.w += a.w;
    }
    float di = dinv[node];
    float av[4] = {acc.x, acc.y, acc.z, acc.w};
    int cbase = q * 4;
#pragma unroll
    for (int i = 0; i < 4; i++) {
        int c = cbase + i;
        if (c < NC) {
            size_t o = (size_t)node * NC + c;
            v[o] = v[o] + di * av[i] + b2[c];   // v aliases s2; own-slot read-modify-write
        }
    }
}

// ---------------- log_softmax ----------------

__global__ void final_kernel(const float* __restrict__ v, int n, float* __restrict__ out) {
    int node = blockIdx.x * blockDim.x + threadIdx.x;
    if (node >= n) return;
    const float* vp = v + (size_t)node * NC;
    float t[NC];
    float mx = -1e30f;
#pragma unroll
    for (int c = 0; c < NC; c++) {
        t[c] = vp[c];
        mx = fmaxf(mx, t[c]);
    }
    float se = 0.f;
#pragma unroll
    for (int c = 0; c < NC; c++) se += expf(t[c] - mx);
    float ls = logf(se);
    float* op = out + (size_t)node * NC;
#pragma unroll
    for (int c = 0; c < NC; c++) op[c] = t[c] - mx - ls;
}

// ---------------- launch ----------------

extern "C" void kernel_launch(void* const* d_in, const int* in_sizes, int n_in,
                              void* d_out, int out_size, void* d_ws, size_t ws_size,
                              hipStream_t stream) {
    const float* x    = (const float*)d_in[0];
    const int*   ei   = (const int*)d_in[1];
    const float* w10  = (const float*)d_in[2];
    const float* w11  = (const float*)d_in[3];
    const float* b1   = (const float*)d_in[4];
    const float* w20  = (const float*)d_in[5];
    const float* w21  = (const float*)d_in[6];
    const float* b2   = (const float*)d_in[7];
    float* out = (float*)d_out;

    int n = in_sizes[0] / N_FEAT;   // 100000
    int E = in_sizes[1] / 2;        // 1600000
    const int* src = ei;
    const int* dst = ei + E;

    auto align256 = [](size_t v) { return (v + 255) & ~(size_t)255; };

    size_t off = 0;
    int*   degi   = (int*)((char*)d_ws + off);   off = align256(off + (size_t)n * 4);
    int*   cnt    = (int*)((char*)d_ws + off);   off = align256(off + (size_t)n * 4);
    size_t zero_bytes = off;                     // degi + cnt zeroed
    int*   rowptr = (int*)((char*)d_ws + off);   off = align256(off + (size_t)(n + 1) * 4);
    int*   bsums  = (int*)((char*)d_ws + off);   off = align256(off + 512);
    int*   esrc   = (int*)((char*)d_ws + off);   off = align256(off + (size_t)E * 4);
    float* dinv   = (float*)((char*)d_ws + off); off = align256(off + (size_t)n * 4);
    float* s1     = (float*)((char*)d_ws + off); off = align256(off + (size_t)n * HID * 4);  // aliased as h
    float* t1s    = (float*)((char*)d_ws + off); off = align256(off + (size_t)n * HID * 4);  // aliased as ps16
    float* s2     = (float*)((char*)d_ws + off); off = align256(off + (size_t)n * NC * 4);   // aliased as v

    float* h    = s1;     // in-place
    float* ps16 = t1s;    // reuse (t1s dead after gather_h)
    float* v    = s2;     // in-place

    hipMemsetAsync(d_ws, 0, zero_bytes, stream);

    const int B = TPB;
    int nb_scan = (n + SCAN_CHUNK - 1) / SCAN_CHUNK;

    deg_kernel<<<(E + B - 1) / B, B, 0, stream>>>(dst, E, degi);
    dinv_kernel<<<(n + B - 1) / B, B, 0, stream>>>(degi, n, dinv);
    scan_blocks<<<nb_scan, B, 0, stream>>>(degi, n, rowptr, bsums);
    scan_bsums<<<1, 64, 0, stream>>>(bsums, nb_scan);
    scan_add<<<(n + B - 1) / B, B, 0, stream>>>(rowptr, n, bsums, E);
    fill_kernel<<<(E + B - 1) / B, B, 0, stream>>>(src, dst, E, rowptr, cnt, esrc);

    node1_kernel<<<(n + B - 1) / B, B, 0, stream>>>(x, w10, w11, dinv, n, s1, t1s);
    {
        long long tot = (long long)n * 4;
        gather_h<<<(int)((tot + B - 1) / B), B, 0, stream>>>(rowptr, esrc, (const float4*)t1s,
                                                            dinv, b1, (float4*)h, n);
    }
    node2_kernel<<<(n + B - 1) / B, B, 0, stream>>>(h, dinv, w20, w21, n, s2, ps16);
    {
        long long tot = (long long)n * 4;
        gather_v<<<(int)((tot + B - 1) / B), B, 0, stream>>>(rowptr, esrc, (const float4*)ps16,
                                                            dinv, b2, v, n);
    }
    final_kernel<<<(n + B - 1) / B, B, 0, stream>>>(v, n, out);
}

// Round 3
// 200.924 us; speedup vs baseline: 1.9104x; 1.7009x over previous
//
#include <hip/hip_runtime.h>

#define N_FEAT 50
#define HID 16
#define NC 10
#define TPB 256

#define NPB 512          // nodes per bucket (power of 2)
#define NPB_SHIFT 9
#define CAP 10240        // edge capacity per bucket (mean 8192, +22 sigma)
#define BIN_VPT 32
#define BIN_CHUNK (TPB * BIN_VPT)   // 8192 edges per block

// ---------------- init: bucket cursors ----------------

__global__ void init_kernel(int* __restrict__ bcur) {
    int t = threadIdx.x;                 // one block of 256
    bcur[t] = t * CAP;
}

// ---------------- binning: edges -> bucket-contiguous packed words ----------------
// word = (src << 9) | (dst & 511); bucket = dst >> 9

__global__ void bin_kernel(const int* __restrict__ src, const int* __restrict__ dst, int E,
                           int* __restrict__ bcur, int* __restrict__ ebuf) {
    __shared__ int hist[256];
    __shared__ int base[256];
    int t = threadIdx.x;
    hist[t] = 0;
    __syncthreads();

    int blockBase = blockIdx.x * BIN_CHUNK;
    // phase A: histogram buckets
#pragma unroll
    for (int i = 0; i < BIN_VPT; i++) {
        int e = blockBase + i * TPB + t;
        if (e < E) {
            int d = dst[e];
            atomicAdd(&hist[d >> NPB_SHIFT], 1);
        }
    }
    __syncthreads();
    // phase B: reserve global runs (one atomic per block,bucket)
    int c = hist[t];
    base[t] = atomicAdd(&bcur[t], c);   // bcur sized 256; c==0 harmless
    hist[t] = 0;                        // reuse as local cursor
    __syncthreads();
    // phase C: scatter packed words into runs
#pragma unroll
    for (int i = 0; i < BIN_VPT; i++) {
        int e = blockBase + i * TPB + t;
        if (e < E) {
            int d = dst[e];
            int s = src[e];
            int b = d >> NPB_SHIFT;
            int off = atomicAdd(&hist[b], 1);
            ebuf[base[b] + off] = (s << NPB_SHIFT) | (d & (NPB - 1));
        }
    }
}

// ---------------- per-bucket CSR build + degree/dinv ----------------
// one block per bucket

__global__ void csr_kernel(const int* __restrict__ bcur, const int* __restrict__ ebuf,
                           int n,
                           int* __restrict__ esrcS, int2* __restrict__ rowbe,
                           float* __restrict__ dinv) {
    __shared__ int hist[NPB];
    __shared__ int scanx[NPB];
    __shared__ int cur[NPB];
    __shared__ int lds2[TPB];
    int t = threadIdx.x;
    int b = blockIdx.x;
    int bBase = b * CAP;
    int count = bcur[b] - bBase;

    hist[t] = 0; hist[t + TPB] = 0;
    __syncthreads();

    // pass 1: local histogram
    for (int k = t; k < count; k += TPB) {
        int w = ebuf[bBase + k];
        atomicAdd(&hist[w & (NPB - 1)], 1);
    }
    __syncthreads();

    // exclusive scan over 512 (2 elems/thread)
    int v0 = hist[2 * t];
    int v1 = hist[2 * t + 1];
    lds2[t] = v0 + v1;
    __syncthreads();
    for (int off = 1; off < TPB; off <<= 1) {
        int val = lds2[t];
        int add = (t >= off) ? lds2[t - off] : 0;
        __syncthreads();
        lds2[t] = val + add;
        __syncthreads();
    }
    int exclPair = (t == 0) ? 0 : lds2[t - 1];
    scanx[2 * t] = exclPair;
    scanx[2 * t + 1] = exclPair + v0;
    cur[2 * t] = exclPair;
    cur[2 * t + 1] = exclPair + v0;
    __syncthreads();

    // emit rowbe + dinv (coalesced)
#pragma unroll
    for (int i = 0; i < 2; i++) {
        int l = t + i * TPB;
        int node = b * NPB + l;
        if (node < n) {
            int deg = hist[l];
            int beg = bBase + scanx[l];
            rowbe[node] = make_int2(beg, beg + deg);
            dinv[node] = (deg > 0) ? rsqrtf((float)deg) : 0.0f;
        }
    }

    // pass 2: counting-sort srcs into esrcS
    for (int k = t; k < count; k += TPB) {
        int w = ebuf[bBase + k];
        int dl = w & (NPB - 1);
        int pos = atomicAdd(&cur[dl], 1);
        esrcS[bBase + pos] = w >> NPB_SHIFT;
    }
}

// ---------------- layer-1 node matmuls ----------------
// s1 = x @ w1_0 ; t1s = dinv[node] * (x @ w1_1)

__global__ void node1_kernel(const float* __restrict__ x,
                             const float* __restrict__ w10,
                             const float* __restrict__ w11,
                             const float* __restrict__ dinv,
                             int n,
                             float* __restrict__ s1,
                             float* __restrict__ t1s) {
    __shared__ float sw0[N_FEAT * HID];
    __shared__ float sw1[N_FEAT * HID];
    __shared__ float sx[TPB * (N_FEAT + 1)];
    for (int i = threadIdx.x; i < N_FEAT * HID; i += TPB) {
        sw0[i] = w10[i];
        sw1[i] = w11[i];
    }
    int base = blockIdx.x * TPB;
    int cnt = n - base; if (cnt > TPB) cnt = TPB;
    for (int idx = threadIdx.x; idx < cnt * N_FEAT; idx += TPB) {
        int ln = idx / N_FEAT;
        int c  = idx - ln * N_FEAT;
        sx[ln * (N_FEAT + 1) + c] = x[(size_t)base * N_FEAT + idx];
    }
    __syncthreads();
    int local = threadIdx.x;
    int node = base + local;
    if (node >= n) return;

    float xr[N_FEAT];
#pragma unroll
    for (int i = 0; i < N_FEAT; i++) xr[i] = sx[local * (N_FEAT + 1) + i];

    float di = dinv[node];
    float* s1p = s1 + (size_t)node * HID;
    float* tp  = t1s + (size_t)node * HID;
#pragma unroll
    for (int j = 0; j < HID; j++) {
        float a0 = 0.f, a1 = 0.f;
#pragma unroll
        for (int i = 0; i < N_FEAT; i++) {
            a0 += xr[i] * sw0[i * HID + j];
            a1 += xr[i] * sw1[i * HID + j];
        }
        s1p[j] = a0;
        tp[j]  = di * a1;
    }
}

// ---------------- layer-1 gather + relu (in-place h over s1) ----------------

__global__ void gather_h(const int2* __restrict__ rowbe, const int* __restrict__ esrc,
                         const float4* __restrict__ t1s4,
                         const float* __restrict__ dinv,
                         const float* __restrict__ b1,
                         float4* __restrict__ h4,
                         int n) {
    int t = blockIdx.x * blockDim.x + threadIdx.x;
    int node = t >> 2;
    int q = t & 3;
    if (node >= n) return;
    int2 be = rowbe[node];
    float4 acc = make_float4(0.f, 0.f, 0.f, 0.f);
    int k = be.x;
    for (; k + 1 < be.y; k += 2) {
        int s0 = esrc[k];
        int s1i = esrc[k + 1];
        float4 a = t1s4[(size_t)s0 * 4 + q];
        float4 b = t1s4[(size_t)s1i * 4 + q];
        acc.x += a.x + b.x; acc.y += a.y + b.y;
        acc.z += a.z + b.z; acc.w += a.w + b.w;
    }
    if (k < be.y) {
        int s0 = esrc[k];
        float4 a = t1s4[(size_t)s0 * 4 + q];
        acc.x += a.x; acc.y += a.y; acc.z += a.z; acc.w += a.w;
    }
    float di = dinv[node];
    float4 s = h4[(size_t)node * 4 + q];
    float4 bb = ((const float4*)b1)[q];
    float4 r;
    r.x = fmaxf(s.x + di * acc.x + bb.x, 0.f);
    r.y = fmaxf(s.y + di * acc.y + bb.y, 0.f);
    r.z = fmaxf(s.z + di * acc.z + bb.z, 0.f);
    r.w = fmaxf(s.w + di * acc.w + bb.w, 0.f);
    h4[(size_t)node * 4 + q] = r;
}

// ---------------- layer-2 node matmuls ----------------

__global__ void node2_kernel(const float* __restrict__ h,
                             const float* __restrict__ dinv,
                             const float* __restrict__ w20,
                             const float* __restrict__ w21,
                             int n,
                             float* __restrict__ s2,
                             float* __restrict__ ps16) {
    __shared__ float sw0[HID * NC];
    __shared__ float sw1[HID * NC];
    for (int i = threadIdx.x; i < HID * NC; i += TPB) {
        sw0[i] = w20[i];
        sw1[i] = w21[i];
    }
    __syncthreads();
    int node = blockIdx.x * blockDim.x + threadIdx.x;
    if (node >= n) return;

    float hr[HID];
    const float* hp = h + (size_t)node * HID;
#pragma unroll
    for (int j = 0; j < HID; j++) hr[j] = hp[j];

    float di = dinv[node];
    float* s2p = s2 + (size_t)node * NC;
    float* pp  = ps16 + (size_t)node * 16;
#pragma unroll
    for (int c = 0; c < NC; c++) {
        float a0 = 0.f, a1 = 0.f;
#pragma unroll
        for (int j = 0; j < HID; j++) {
            a0 += hr[j] * sw0[j * NC + c];
            a1 += hr[j] * sw1[j * NC + c];
        }
        s2p[c] = a0;
        pp[c]  = di * a1;
    }
#pragma unroll
    for (int c = NC; c < 16; c++) pp[c] = 0.f;
}

// ---------------- layer-2 gather (in-place v over s2) ----------------

__global__ void gather_v(const int2* __restrict__ rowbe, const int* __restrict__ esrc,
                         const float4* __restrict__ ps4,
                         const float* __restrict__ dinv,
                         const float* __restrict__ b2,
                         float* __restrict__ v,
                         int n) {
    int t = blockIdx.x * blockDim.x + threadIdx.x;
    int node = t >> 2;
    int q = t & 3;
    if (node >= n) return;
    int2 be = rowbe[node];
    float4 acc = make_float4(0.f, 0.f, 0.f, 0.f);
    int k = be.x;
    for (; k + 1 < be.y; k += 2) {
        int s0 = esrc[k];
        int s1i = esrc[k + 1];
        float4 a = ps4[(size_t)s0 * 4 + q];
        float4 b = ps4[(size_t)s1i * 4 + q];
        acc.x += a.x + b.x; acc.y += a.y + b.y;
        acc.z += a.z + b.z; acc.w += a.w + b.w;
    }
    if (k < be.y) {
        int s0 = esrc[k];
        float4 a = ps4[(size_t)s0 * 4 + q];
        acc.x += a.x; acc.y += a.y; acc.z += a.z; acc.w += a.w;
    }
    float di = dinv[node];
    float av[4] = {acc.x, acc.y, acc.z, acc.w};
    int cbase = q * 4;
#pragma unroll
    for (int i = 0; i < 4; i++) {
        int c = cbase + i;
        if (c < NC) {
            size_t o = (size_t)node * NC + c;
            v[o] = v[o] + di * av[i] + b2[c];
        }
    }
}

// ---------------- log_softmax ----------------

__global__ void final_kernel(const float* __restrict__ v, int n, float* __restrict__ out) {
    int node = blockIdx.x * blockDim.x + threadIdx.x;
    if (node >= n) return;
    const float* vp = v + (size_t)node * NC;
    float t[NC];
    float mx = -1e30f;
#pragma unroll
    for (int c = 0; c < NC; c++) {
        t[c] = vp[c];
        mx = fmaxf(mx, t[c]);
    }
    float se = 0.f;
#pragma unroll
    for (int c = 0; c < NC; c++) se += expf(t[c] - mx);
    float ls = logf(se);
    float* op = out + (size_t)node * NC;
#pragma unroll
    for (int c = 0; c < NC; c++) op[c] = t[c] - mx - ls;
}

// ---------------- launch ----------------

extern "C" void kernel_launch(void* const* d_in, const int* in_sizes, int n_in,
                              void* d_out, int out_size, void* d_ws, size_t ws_size,
                              hipStream_t stream) {
    const float* x    = (const float*)d_in[0];
    const int*   ei   = (const int*)d_in[1];
    const float* w10  = (const float*)d_in[2];
    const float* w11  = (const float*)d_in[3];
    const float* b1   = (const float*)d_in[4];
    const float* w20  = (const float*)d_in[5];
    const float* w21  = (const float*)d_in[6];
    const float* b2   = (const float*)d_in[7];
    float* out = (float*)d_out;

    int n = in_sizes[0] / N_FEAT;   // 100000
    int E = in_sizes[1] / 2;        // 1600000
    const int* src = ei;
    const int* dst = ei + E;

    int NB = (n + NPB - 1) >> NPB_SHIFT;   // 196

    auto align256 = [](size_t v) { return (v + 255) & ~(size_t)255; };

    size_t off = 0;
    int*   bcur  = (int*)((char*)d_ws + off);   off = align256(off + 256 * 4);
    int*   ebuf  = (int*)((char*)d_ws + off);   off = align256(off + (size_t)NB * CAP * 4);
    int*   esrcS = (int*)((char*)d_ws + off);   off = align256(off + (size_t)NB * CAP * 4);
    int2*  rowbe = (int2*)((char*)d_ws + off);  off = align256(off + (size_t)n * 8);
    float* dinv  = (float*)((char*)d_ws + off); off = align256(off + (size_t)n * 4);
    float* s1    = (float*)((char*)d_ws + off); off = align256(off + (size_t)n * HID * 4);  // aliased as h
    float* t1s   = (float*)((char*)d_ws + off); off = align256(off + (size_t)n * HID * 4);  // aliased as ps16
    float* s2    = (float*)((char*)d_ws + off); off = align256(off + (size_t)n * NC * 4);   // aliased as v

    float* h    = s1;
    float* ps16 = t1s;
    float* v    = s2;

    const int B = TPB;
    init_kernel<<<1, 256, 0, stream>>>(bcur);
    bin_kernel<<<(E + BIN_CHUNK - 1) / BIN_CHUNK, B, 0, stream>>>(src, dst, E, bcur, ebuf);
    csr_kernel<<<NB, B, 0, stream>>>(bcur, ebuf, n, esrcS, rowbe, dinv);

    node1_kernel<<<(n + B - 1) / B, B, 0, stream>>>(x, w10, w11, dinv, n, s1, t1s);
    {
        long long tot = (long long)n * 4;
        gather_h<<<(int)((tot + B - 1) / B), B, 0, stream>>>(rowbe, esrcS, (const float4*)t1s,
                                                            dinv, b1, (float4*)h, n);
    }
    node2_kernel<<<(n + B - 1) / B, B, 0, stream>>>(h, dinv, w20, w21, n, s2, ps16);
    {
        long long tot = (long long)n * 4;
        gather_v<<<(int)((tot + B - 1) / B), B, 0, stream>>>(rowbe, esrcS, (const float4*)ps16,
                                                            dinv, b2, v, n);
    }
    final_kernel<<<(n + B - 1) / B, B, 0, stream>>>(v, n, out);
}